// Round 8
// baseline (108.083 us; speedup 1.0000x reference)
//
#include <hip/hip_runtime.h>
#include <stdint.h>

#define BATCH 32
#define NA    8400
#define NL    80
#define NH    256
#define NK    300
#define NBIN  8192   // 13-bit key = mapped-u32 >> 19
#define RPB   1050   // rows per producer block (NA/8)

// output float offsets (concatenated return order)
#define OUT0 0                       // init_reference_points (32,300,4)
#define OUT1 38400                   // target                (32,300,256)
#define OUT2 2496000                 // enc_topk_logits       (32,300,80)
#define OUT3 3264000                 // enc_topk_bboxes       (32,300,4)

// ws layout: ws_u 32*8400 u32 = 1,075,200 B ; done flags 32 u32 after it
#define WS_DONE_OFF 1075200

__device__ __forceinline__ unsigned mapf(float f) {
    unsigned u = __float_as_uint(f);
    return (u & 0x80000000u) ? ~u : (u | 0x80000000u);
}

// One kernel, 256 blocks x 1024 threads. Block (b=bid&31, sub=bid>>5):
//   phase 1: class-max for rows [sub*1050,(sub+1)*1050) of batch b -> ws_u
//   per-batch sync: release fence + agent atomicAdd; spin till all 8 arrive.
//     (grid=256=CU count and 2-blocks/CU capacity -> all blocks resident at
//      launch; spin waits only on same-batch blocks -> no deadlock. This
//      replaces round-7's grid.sync(), which cost ~35us.)
//   phase 2: redundant exact top-300 select (LDS hist + shuffle suffix scan +
//     rank-by-comparison), then gather queries q≡sub (mod 8).
__global__ __launch_bounds__(1024) void fused_kernel(
        const float*    __restrict__ cls,
        const float*    __restrict__ coord,
        const float*    __restrict__ mem,
        unsigned*       __restrict__ ws_u,
        unsigned*       __restrict__ done,
        float*          __restrict__ out) {
    __shared__ unsigned hist[NBIN];                 // 32 KB
    __shared__ unsigned long long keys[1024];       // 8 KB
    __shared__ int ord[NK];
    __shared__ unsigned wsum[16], wsuf[16];
    __shared__ unsigned s_thr, s_count;

    int tid  = threadIdx.x;
    int lane = tid & 63;
    int wid  = tid >> 6;
    int b    = blockIdx.x & 31;
    int sub  = blockIdx.x >> 5;                     // 0..7

    // ---- phase 1: class-max for this block's 1050-row slice ----
    {
        int r4 = tid >> 2;                          // 0..255
        int s4 = tid & 3;
        size_t rowbase = (size_t)b * NA + (size_t)sub * RPB;
#pragma unroll
        for (int p = 0; p < 5; ++p) {
            int r = p * 256 + r4;
            if (r < RPB) {
                const float4* rp = (const float4*)(cls + (rowbase + r) * NL) + s4 * 5;
                float m = -3.4e38f;
#pragma unroll
                for (int e = 0; e < 5; ++e) {
                    float4 w = rp[e];
                    m = fmaxf(m, fmaxf(fmaxf(w.x, w.y), fmaxf(w.z, w.w)));
                }
                m = fmaxf(m, __shfl_xor(m, 1));
                m = fmaxf(m, __shfl_xor(m, 2));
                if (s4 == 0) ws_u[rowbase + r] = mapf(m);
            }
        }
    }

    // ---- per-batch arrive + spin (done[] zeroed by memset node each replay)
    __syncthreads();
    __threadfence();                                 // release ws_u slice
    if (tid == 0) {
        __hip_atomic_fetch_add(&done[b], 1u, __ATOMIC_RELEASE,
                               __HIP_MEMORY_SCOPE_AGENT);
        while (__hip_atomic_load(&done[b], __ATOMIC_ACQUIRE,
                                 __HIP_MEMORY_SCOPE_AGENT) < 8u) {
            __builtin_amdgcn_s_sleep(1);
        }
    }
    __syncthreads();

    // ---- phase 2: select + gather (round-5 passing code; ws_u reads are
    //      agent-scope relaxed atomics so they can't hit stale local cache) --
    const unsigned* ub = ws_u + b * NA;

    unsigned v[9];
#pragma unroll
    for (int k = 0; k < 9; ++k) {
        int i = tid + k * 1024;
        v[k] = (i < NA) ? __hip_atomic_load(&ub[i], __ATOMIC_RELAXED,
                                            __HIP_MEMORY_SCOPE_AGENT)
                        : 0u;                        // 0 -> bin 0, never selected
    }

    for (int i = tid; i < NBIN; i += 1024) hist[i] = 0;
    if (tid == 0) s_count = 0;
    __syncthreads();

#pragma unroll
    for (int k = 0; k < 9; ++k) {
        int i = tid + k * 1024;
        if (i < NA) atomicAdd(&hist[v[k] >> 19], 1u);
    }
    __syncthreads();

    // hierarchical suffix scan over 8192 bins; thread owns [tid*8, tid*8+8)
    unsigned base = tid * 8;
    unsigned h[8];
#pragma unroll
    for (int j = 0; j < 8; ++j) h[j] = hist[base + j];
    unsigned L = 0;
#pragma unroll
    for (int j = 0; j < 8; ++j) L += h[j];
    unsigned s = L;                                  // inclusive suffix within wave
#pragma unroll
    for (int off = 1; off < 64; off <<= 1) {
        unsigned t = __shfl_down(s, off);
        if (lane + off < 64) s += t;
    }
    if (lane == 0) wsum[wid] = s;
    __syncthreads();
    if (tid == 0) {
        unsigned acc = 0;
        for (int w = 15; w >= 0; --w) { acc += wsum[w]; wsuf[w] = acc; }
    }
    __syncthreads();
    unsigned above = (wid < 15 ? wsuf[wid + 1] : 0u) + (s - L);
    unsigned acc = above;
#pragma unroll
    for (int j = 7; j >= 0; --j) {
        unsigned S = acc + h[j];
        if (S >= (unsigned)NK && acc < (unsigned)NK) s_thr = base + (unsigned)j;
        acc = S;
    }
    __syncthreads();

    // collect candidates from registers (no global re-read)
    unsigned T = s_thr;
#pragma unroll
    for (int k = 0; k < 9; ++k) {
        int i = tid + k * 1024;
        if (i < NA && (v[k] >> 19) >= T) {
            unsigned pos = atomicAdd(&s_count, 1u);
            if (pos < 1024) keys[pos] = ((unsigned long long)(~v[k]) << 32) | (unsigned)i;
        }
    }
    __syncthreads();

    // rank-by-comparison: key asc == (u desc, idx asc); deterministic
    unsigned count = s_count < 1024u ? s_count : 1024u;
    if (tid < (int)count) {
        unsigned long long mykey = keys[tid];
        int rank = 0;
        for (unsigned j = 0; j < count; ++j) rank += (keys[j] < mykey);
        if (rank < NK) ord[rank] = (int)(mykey & 0xFFFFFFFFull);
    }
    __syncthreads();

    // gather: this block handles queries q ≡ sub (mod 8); one wave per query
    for (int q = sub + 8 * wid; q < NK; q += 8 * 16) {
        int idx = ord[q];
        size_t srow = (size_t)b * NA + (size_t)idx;
        size_t drow = (size_t)b * NK + (size_t)q;

        const float4* msrc = (const float4*)(mem + srow * NH);
        float4*       mdst = (float4*)(out + OUT1 + drow * NH);
        mdst[lane] = msrc[lane];

        if (lane < 20) {
            const float4* lsrc = (const float4*)(cls + srow * NL);
            float4*       ldst = (float4*)(out + OUT2 + drow * NL);
            ldst[lane] = lsrc[lane];
        }
        if (lane == 0) {
            float4 c = ((const float4*)(coord + srow * 4))[0];
            ((float4*)(out + OUT0 + drow * 4))[0] = c;
            float4 sg;
            sg.x = 1.0f / (1.0f + __expf(-c.x));
            sg.y = 1.0f / (1.0f + __expf(-c.y));
            sg.z = 1.0f / (1.0f + __expf(-c.z));
            sg.w = 1.0f / (1.0f + __expf(-c.w));
            ((float4*)(out + OUT3 + drow * 4))[0] = sg;
        }
    }
}

extern "C" void kernel_launch(void* const* d_in, const int* in_sizes, int n_in,
                              void* d_out, int out_size, void* d_ws, size_t ws_size,
                              hipStream_t stream) {
    const float* cls   = (const float*)d_in[0]; // (32,8400,80)
    const float* coord = (const float*)d_in[1]; // (32,8400,4)
    const float* mem   = (const float*)d_in[2]; // (32,8400,256)
    // d_in[3] (sources_last_element) unused by the reference

    unsigned* ws_u = (unsigned*)d_ws;
    unsigned* done = (unsigned*)((char*)d_ws + WS_DONE_OFF);
    float*    out  = (float*)d_out;

    hipMemsetAsync(done, 0, BATCH * sizeof(unsigned), stream);
    fused_kernel<<<256, 1024, 0, stream>>>(cls, coord, mem, ws_u, done, out);
}

// Round 9
// 39.557 us; speedup vs baseline: 2.7323x; 2.7323x over previous
//
#include <hip/hip_runtime.h>
#include <stdint.h>

#define BATCH 32
#define NA    8400
#define NL    80
#define NH    256
#define NK    300
#define NBIN  8192   // 13-bit key = mapped-u32 >> 19

// output float offsets (concatenated return order)
#define OUT0 0                       // init_reference_points (32,300,4)
#define OUT1 38400                   // target                (32,300,256)
#define OUT2 2496000                 // enc_topk_logits       (32,300,80)
#define OUT3 3264000                 // enc_topk_bboxes       (32,300,4)

__device__ __forceinline__ unsigned mapf(float f) {
    unsigned u = __float_as_uint(f);
    return (u & 0x80000000u) ? ~u : (u | 0x80000000u);
}

// Kernel 1: per-(b,a) max over L=80, store monotone-mapped u32.
// 4 threads/row, float4 loads, 64 rows per 256-thread block. BW-bound
// (~13-15us; R6 showed LDS-staged fully-coalesced variant is equal, so
// this is at the HBM floor).
__global__ __launch_bounds__(256) void cls_max_kernel(const float* __restrict__ cls,
                                                      unsigned* __restrict__ out_u) {
    int tid = threadIdx.x;
    int row = blockIdx.x * 64 + (tid >> 2);
    int sub = tid & 3;
    if (row >= BATCH * NA) return;
    const float4* p = (const float4*)(cls + (size_t)row * NL);
    float m = -3.4e38f;
#pragma unroll
    for (int q = 0; q < 5; ++q) {
        float4 v = p[sub + q * 4];
        m = fmaxf(m, fmaxf(fmaxf(v.x, v.y), fmaxf(v.z, v.w)));
    }
    m = fmaxf(m, __shfl_xor(m, 1));
    m = fmaxf(m, __shfl_xor(m, 2));
    if (sub == 0) out_u[row] = mapf(m);
}

// Kernel 2 (fused select + gather): 8 blocks per batch, 1024 threads.
// Each block redundantly computes the exact top-300 of its batch
// (registers + LDS 8192-bin histogram + shuffle suffix-scan + split
// rank-by-comparison), then gathers queries q≡sub (mod 8).
// R7/R8 lesson: do NOT replace this redundancy with cross-block sync —
// grid.sync cost ~35us, spin+agent-atomics cost ~73us.
__global__ __launch_bounds__(1024) void select_gather_kernel(
        const unsigned* __restrict__ u_in,
        const float*    __restrict__ cls,
        const float*    __restrict__ coord,
        const float*    __restrict__ mem,
        float*          __restrict__ out) {
    __shared__ unsigned hist[NBIN];                 // 32 KB
    __shared__ unsigned long long keys[1024];       // 8 KB
    __shared__ unsigned rnk[1024];                  // 4 KB
    __shared__ int ord[NK];
    __shared__ unsigned wsum[16], wsuf[16];
    __shared__ unsigned s_thr, s_count;

    int tid  = threadIdx.x;
    int lane = tid & 63;
    int wid  = tid >> 6;
    int b    = blockIdx.x >> 3;
    int sub  = blockIdx.x & 7;
    const unsigned* ub = u_in + b * NA;

    // issue global loads FIRST (HBM/L3 latency hides under hist zeroing)
    unsigned v[9];
#pragma unroll
    for (int k = 0; k < 9; ++k) {
        int i = tid + k * 1024;
        v[k] = (i < NA) ? ub[i] : 0u;               // 0 -> bin 0, never selected
    }

    for (int i = tid; i < NBIN; i += 1024) hist[i] = 0;
    if (tid == 0) s_count = 0;
    rnk[tid] = 0;
    __syncthreads();

#pragma unroll
    for (int k = 0; k < 9; ++k) {
        int i = tid + k * 1024;
        if (i < NA) atomicAdd(&hist[v[k] >> 19], 1u);
    }
    __syncthreads();

    // hierarchical suffix scan over 8192 bins; thread owns [tid*8, tid*8+8)
    unsigned base = tid * 8;
    unsigned h[8];
#pragma unroll
    for (int j = 0; j < 8; ++j) h[j] = hist[base + j];
    unsigned L = 0;
#pragma unroll
    for (int j = 0; j < 8; ++j) L += h[j];
    unsigned s = L;                                  // inclusive suffix within wave
#pragma unroll
    for (int off = 1; off < 64; off <<= 1) {
        unsigned t = __shfl_down(s, off);
        if (lane + off < 64) s += t;
    }
    if (lane == 0) wsum[wid] = s;
    __syncthreads();
    if (tid == 0) {
        unsigned acc = 0;
        for (int w = 15; w >= 0; --w) { acc += wsum[w]; wsuf[w] = acc; }
    }
    __syncthreads();
    unsigned above = (wid < 15 ? wsuf[wid + 1] : 0u) + (s - L);
    unsigned acc = above;
#pragma unroll
    for (int j = 7; j >= 0; --j) {
        unsigned S = acc + h[j];
        if (S >= (unsigned)NK && acc < (unsigned)NK) s_thr = base + (unsigned)j;
        acc = S;
    }
    __syncthreads();

    // collect candidates from registers (no global re-read)
    unsigned T = s_thr;
#pragma unroll
    for (int k = 0; k < 9; ++k) {
        int i = tid + k * 1024;
        if (i < NA && (v[k] >> 19) >= T) {
            unsigned pos = atomicAdd(&s_count, 1u);
            if (pos < 1024) keys[pos] = ((unsigned long long)(~v[k]) << 32) | (unsigned)i;
        }
    }
    __syncthreads();

    // split rank-by-comparison: key asc == (u desc, idx asc). Candidate c's
    // comparisons are halved across threads c and c+512 (one LDS atomicAdd
    // each), halving the ~370-iteration serial broadcast chain.
    unsigned count = s_count < 1024u ? s_count : 1024u;
    unsigned half  = count >> 1;
    int c  = (tid < 512) ? tid : tid - 512;
    if ((unsigned)c < count) {
        unsigned j0 = (tid < 512) ? 0u : half;
        unsigned j1 = (tid < 512) ? half : count;
        unsigned long long mykey = keys[c];
        unsigned r = 0;
        for (unsigned j = j0; j < j1; ++j) r += (keys[j] < mykey);
        if (r) atomicAdd(&rnk[c], r);
    }
    __syncthreads();
    if (tid < (int)count) {
        unsigned rk = rnk[tid];
        if (rk < NK) ord[rk] = (int)(keys[tid] & 0xFFFFFFFFull);
    }
    __syncthreads();

    // gather: this block handles queries q ≡ sub (mod 8); one wave per query
    for (int q = sub + 8 * wid; q < NK; q += 8 * 16) {
        int idx = ord[q];
        size_t srow = (size_t)b * NA + (size_t)idx;
        size_t drow = (size_t)b * NK + (size_t)q;

        const float4* msrc = (const float4*)(mem + srow * NH);
        float4*       mdst = (float4*)(out + OUT1 + drow * NH);
        mdst[lane] = msrc[lane];

        if (lane < 20) {
            const float4* lsrc = (const float4*)(cls + srow * NL);
            float4*       ldst = (float4*)(out + OUT2 + drow * NL);
            ldst[lane] = lsrc[lane];
        }
        if (lane == 0) {
            float4 cc = ((const float4*)(coord + srow * 4))[0];
            ((float4*)(out + OUT0 + drow * 4))[0] = cc;
            float4 sg;
            sg.x = 1.0f / (1.0f + __expf(-cc.x));
            sg.y = 1.0f / (1.0f + __expf(-cc.y));
            sg.z = 1.0f / (1.0f + __expf(-cc.z));
            sg.w = 1.0f / (1.0f + __expf(-cc.w));
            ((float4*)(out + OUT3 + drow * 4))[0] = sg;
        }
    }
}

extern "C" void kernel_launch(void* const* d_in, const int* in_sizes, int n_in,
                              void* d_out, int out_size, void* d_ws, size_t ws_size,
                              hipStream_t stream) {
    const float* cls   = (const float*)d_in[0]; // (32,8400,80)
    const float* coord = (const float*)d_in[1]; // (32,8400,4)
    const float* mem   = (const float*)d_in[2]; // (32,8400,256)
    // d_in[3] (sources_last_element) unused by the reference

    unsigned* ws_u = (unsigned*)d_ws;           // 32*8400 u32
    float*    out  = (float*)d_out;

    cls_max_kernel<<<(BATCH * NA) / 64, 256, 0, stream>>>(cls, ws_u);
    select_gather_kernel<<<BATCH * 8, 1024, 0, stream>>>(ws_u, cls, coord, mem, out);
}

// Round 10
// 35.084 us; speedup vs baseline: 3.0807x; 1.1275x over previous
//
#include <hip/hip_runtime.h>
#include <stdint.h>

#define BATCH 32
#define NA    8400
#define NL    80
#define NH    256
#define NK    300
#define NBIN  8192   // 13-bit key = mapped-u32 >> 19

// output float offsets (concatenated return order)
#define OUT0 0                       // init_reference_points (32,300,4)
#define OUT1 38400                   // target                (32,300,256)
#define OUT2 2496000                 // enc_topk_logits       (32,300,80)
#define OUT3 3264000                 // enc_topk_bboxes       (32,300,4)

__device__ __forceinline__ unsigned mapf(float f) {
    unsigned u = __float_as_uint(f);
    return (u & 0x80000000u) ? ~u : (u | 0x80000000u);
}

// Kernel 1: per-(b,a) max over L=80, store monotone-mapped u32.
// 4 threads/row, float4 loads, 64 rows per 256-thread block. BW-bound
// (~15us; R6 showed an LDS-staged fully-coalesced variant is equal, so this
// is at the empirical HBM floor for this pattern).
__global__ __launch_bounds__(256) void cls_max_kernel(const float* __restrict__ cls,
                                                      unsigned* __restrict__ out_u) {
    int tid = threadIdx.x;
    int row = blockIdx.x * 64 + (tid >> 2);
    int sub = tid & 3;
    if (row >= BATCH * NA) return;
    const float4* p = (const float4*)(cls + (size_t)row * NL);
    float m = -3.4e38f;
#pragma unroll
    for (int q = 0; q < 5; ++q) {
        float4 v = p[sub + q * 4];
        m = fmaxf(m, fmaxf(fmaxf(v.x, v.y), fmaxf(v.z, v.w)));
    }
    m = fmaxf(m, __shfl_xor(m, 1));
    m = fmaxf(m, __shfl_xor(m, 2));
    if (sub == 0) out_u[row] = mapf(m);
}

// Kernel 2 (fused select + gather): 8 blocks per batch, 1024 threads.
// Each block redundantly computes the exact top-300 of its batch
// (registers + LDS 8192-bin histogram + shuffle suffix-scan + barrier-free
// rank-by-comparison), then gathers queries q≡sub (mod 8).
// Session lessons baked in: no cross-block sync (R7 grid.sync +35us, R8
// spin+agent-atomics +73us), no split-rank (R9 +4.9us), no device-scope
// histogram atomics (R4 +55us), k1 access-pattern changes are neutral (R6).
__global__ __launch_bounds__(1024) void select_gather_kernel(
        const unsigned* __restrict__ u_in,
        const float*    __restrict__ cls,
        const float*    __restrict__ coord,
        const float*    __restrict__ mem,
        float*          __restrict__ out) {
    __shared__ unsigned hist[NBIN];                 // 32 KB
    __shared__ unsigned long long keys[1024];       // 8 KB
    __shared__ int ord[NK];
    __shared__ unsigned wsum[16], wsuf[16];
    __shared__ unsigned s_thr, s_count;

    int tid  = threadIdx.x;
    int lane = tid & 63;
    int wid  = tid >> 6;
    int b    = blockIdx.x >> 3;
    int sub  = blockIdx.x & 7;
    const unsigned* ub = u_in + b * NA;

    // issue global loads FIRST (HBM/L2 latency hides under hist zeroing)
    unsigned v[9];
#pragma unroll
    for (int k = 0; k < 9; ++k) {
        int i = tid + k * 1024;
        v[k] = (i < NA) ? ub[i] : 0u;               // 0 -> bin 0, never selected
    }

    for (int i = tid; i < NBIN; i += 1024) hist[i] = 0;
    if (tid == 0) s_count = 0;
    __syncthreads();

#pragma unroll
    for (int k = 0; k < 9; ++k) {
        int i = tid + k * 1024;
        if (i < NA) atomicAdd(&hist[v[k] >> 19], 1u);
    }
    __syncthreads();

    // hierarchical suffix scan over 8192 bins; thread owns [tid*8, tid*8+8)
    unsigned base = tid * 8;
    unsigned h[8];
#pragma unroll
    for (int j = 0; j < 8; ++j) h[j] = hist[base + j];
    unsigned L = 0;
#pragma unroll
    for (int j = 0; j < 8; ++j) L += h[j];
    unsigned s = L;                                  // inclusive suffix within wave
#pragma unroll
    for (int off = 1; off < 64; off <<= 1) {
        unsigned t = __shfl_down(s, off);
        if (lane + off < 64) s += t;
    }
    if (lane == 0) wsum[wid] = s;
    __syncthreads();
    if (tid == 0) {
        unsigned acc = 0;
        for (int w = 15; w >= 0; --w) { acc += wsum[w]; wsuf[w] = acc; }
    }
    __syncthreads();
    unsigned above = (wid < 15 ? wsuf[wid + 1] : 0u) + (s - L);
    unsigned acc = above;
#pragma unroll
    for (int j = 7; j >= 0; --j) {
        unsigned S = acc + h[j];
        if (S >= (unsigned)NK && acc < (unsigned)NK) s_thr = base + (unsigned)j;
        acc = S;
    }
    __syncthreads();

    // collect candidates from registers (no global re-read)
    unsigned T = s_thr;
#pragma unroll
    for (int k = 0; k < 9; ++k) {
        int i = tid + k * 1024;
        if (i < NA && (v[k] >> 19) >= T) {
            unsigned pos = atomicAdd(&s_count, 1u);
            if (pos < 1024) keys[pos] = ((unsigned long long)(~v[k]) << 32) | (unsigned)i;
        }
    }
    __syncthreads();

    // rank-by-comparison: key asc == (u desc, idx asc); deterministic
    unsigned count = s_count < 1024u ? s_count : 1024u;
    if (tid < (int)count) {
        unsigned long long mykey = keys[tid];
        int rank = 0;
        for (unsigned j = 0; j < count; ++j) rank += (keys[j] < mykey);
        if (rank < NK) ord[rank] = (int)(mykey & 0xFFFFFFFFull);
    }
    __syncthreads();

    // gather: this block handles queries q ≡ sub (mod 8); one wave per query
    for (int q = sub + 8 * wid; q < NK; q += 8 * 16) {
        int idx = ord[q];
        size_t srow = (size_t)b * NA + (size_t)idx;
        size_t drow = (size_t)b * NK + (size_t)q;

        const float4* msrc = (const float4*)(mem + srow * NH);
        float4*       mdst = (float4*)(out + OUT1 + drow * NH);
        mdst[lane] = msrc[lane];

        if (lane < 20) {
            const float4* lsrc = (const float4*)(cls + srow * NL);
            float4*       ldst = (float4*)(out + OUT2 + drow * NL);
            ldst[lane] = lsrc[lane];
        }
        if (lane == 0) {
            float4 c = ((const float4*)(coord + srow * 4))[0];
            ((float4*)(out + OUT0 + drow * 4))[0] = c;
            float4 sg;
            sg.x = 1.0f / (1.0f + __expf(-c.x));
            sg.y = 1.0f / (1.0f + __expf(-c.y));
            sg.z = 1.0f / (1.0f + __expf(-c.z));
            sg.w = 1.0f / (1.0f + __expf(-c.w));
            ((float4*)(out + OUT3 + drow * 4))[0] = sg;
        }
    }
}

extern "C" void kernel_launch(void* const* d_in, const int* in_sizes, int n_in,
                              void* d_out, int out_size, void* d_ws, size_t ws_size,
                              hipStream_t stream) {
    const float* cls   = (const float*)d_in[0]; // (32,8400,80)
    const float* coord = (const float*)d_in[1]; // (32,8400,4)
    const float* mem   = (const float*)d_in[2]; // (32,8400,256)
    // d_in[3] (sources_last_element) unused by the reference

    unsigned* ws_u = (unsigned*)d_ws;           // 32*8400 u32
    float*    out  = (float*)d_out;

    cls_max_kernel<<<(BATCH * NA) / 64, 256, 0, stream>>>(cls, ws_u);
    select_gather_kernel<<<BATCH * 8, 1024, 0, stream>>>(ws_u, cls, coord, mem, out);
}